// Round 11
// baseline (225.016 us; speedup 1.0000x reference)
//
#include <hip/hip_runtime.h>
#include <hip/hip_bf16.h>

typedef __attribute__((ext_vector_type(8))) short short8;
typedef __attribute__((ext_vector_type(4))) float f32x4;

#define MFMA16(a,b,c) __builtin_amdgcn_mfma_f32_16x16x32_bf16((a),(b),(c),0,0,0)

constexpr int BHn = 32;     // B*NH
constexpr int Tn  = 2048;
constexpr int Nn  = 512;
constexpr int Dn  = 128;
constexpr int CHn = 64;     // chunk length
constexpr int NCH = Tn / CHn;

static __device__ __forceinline__ unsigned short f2b(float x){
  __hip_bfloat16 h = __float2bfloat16(x);
  return *reinterpret_cast<unsigned short*>(&h);
}

// ---------------- Kernel 1: RoPE(Q) -> bf16 row-major QR (round-0 proven) ----------------
__global__ __launch_bounds__(256) void rope_k(const float* __restrict__ Q,
                                              const float* __restrict__ freqs,
                                              unsigned short* __restrict__ QR){
  int gid = blockIdx.x * 256 + threadIdx.x;
  int np  = gid & 255;
  int t   = gid >> 8;
  float tf = (float)t;
  float f1 = freqs[np], f2 = freqs[np + 256];
  float s1, c1, s2, c2;
  sincosf(tf * f1, &s1, &c1);
  sincosf(tf * f2, &s2, &c2);
  size_t off = (size_t)t * Nn + np;
  for (int bh = 0; bh < BHn; ++bh){
    size_t base = (size_t)bh * Tn * Nn + off;
    float q1 = Q[base], q2 = Q[base + 256];
    QR[base]       = f2b(q1 * c1 - q2 * s1);
    QR[base + 256] = f2b(q2 * c2 + q1 * s2);
  }
}

// ---------------- fragment loaders ----------------
// swizzled loader (works on LDS or a global swizzled image): col ^= (row&7)<<3
__device__ __forceinline__ short8 ldfrag(const unsigned short* buf, int rowbase, int k0, int ld, int lane){
  int row = rowbase + (lane & 15);
  int col = (k0 + ((lane >> 4) << 3)) ^ ((row & 7) << 3);
  return *reinterpret_cast<const short8*>(buf + row * ld + col);
}
// global row-major A/B frag (round-7 proven): lane reads R[rowbase+(lane&15)][k0+(lane>>4)*8 ..+8]
__device__ __forceinline__ short8 gfrag(const unsigned short* Qc, int rowbase, int k0, int lane){
  return *reinterpret_cast<const short8*>(
      Qc + (size_t)(rowbase + (lane & 15)) * Nn + k0 + ((lane >> 4) << 3));
}
// staging writer (round-4 proven): one even row-pair of R into swizzled Rs
__device__ __forceinline__ void stage_Rs(unsigned short* Rs, uint4 a, uint4 b, int dt, int n0){
  *reinterpret_cast<uint4*>(&Rs[ dt      * 512 + (n0 ^ (( dt      & 7) << 3))]) = a;
  *reinterpret_cast<uint4*>(&Rs[(dt + 1) * 512 + (n0 ^ (((dt + 1) & 7) << 3))]) = b;
}

// ---------------- Kernel 2 (parallel): P~ per (bh, chunk) -> global swizzled image -------
// grid 1024 = bh + 32*c, block 256 (4 waves), LDS 64KB -> 2 blocks/CU.
__global__ __launch_bounds__(256) void pt_k(const unsigned short* __restrict__ QR,
                                            const float* __restrict__ gammap,
                                            unsigned short* __restrict__ Pt){
  __shared__ __align__(16) unsigned short Rs[64 * 512];
  __shared__ float gpow[65];
  const int tid = threadIdx.x, w = tid >> 6, lane = tid & 63;
  const int bh = blockIdx.x & 31, c = blockIdx.x >> 5;
  if (tid < 65) gpow[tid] = powf(gammap[0], (float)tid);
  const unsigned short* Qc = QR + (size_t)bh * Tn * Nn + (size_t)(c * CHn) * Nn;
  #pragma unroll
  for (int i = 0; i < 8; ++i){
    int p  = tid + i * 256;
    int dt = (p >> 6) << 1, n0 = (p & 63) << 3;
    const unsigned short* src = Qc + (size_t)dt * Nn + n0;
    uint4 a = *reinterpret_cast<const uint4*>(src);
    uint4 b = *reinterpret_cast<const uint4*>(src + Nn);
    stage_Rs(Rs, a, b, dt, n0);
  }
  __syncthreads();
  f32x4 p0 = {0.f,0.f,0.f,0.f}, p1 = p0, p2 = p0;
  for (int kb = 0; kb < 16; ++kb){
    int k0 = kb * 32;
    if (w == 0){
      short8 f0 = ldfrag(Rs,  0, k0, 512, lane);
      short8 f1 = ldfrag(Rs, 16, k0, 512, lane);
      p0 = MFMA16(f0, f0, p0);      // (0,0)
      p1 = MFMA16(f1, f0, p1);      // (1,0)
      p2 = MFMA16(f1, f1, p2);      // (1,1)
    } else if (w == 1){
      short8 f0 = ldfrag(Rs,  0, k0, 512, lane);
      short8 f1 = ldfrag(Rs, 16, k0, 512, lane);
      short8 f2 = ldfrag(Rs, 32, k0, 512, lane);
      p0 = MFMA16(f2, f0, p0);      // (2,0)
      p1 = MFMA16(f2, f1, p1);      // (2,1)
      p2 = MFMA16(f2, f2, p2);      // (2,2)
    } else if (w == 2){
      short8 f0 = ldfrag(Rs,  0, k0, 512, lane);
      short8 f1 = ldfrag(Rs, 16, k0, 512, lane);
      short8 f3 = ldfrag(Rs, 48, k0, 512, lane);
      p0 = MFMA16(f3, f0, p0);      // (3,0)
      p1 = MFMA16(f3, f1, p1);      // (3,1)
    } else {
      short8 f2 = ldfrag(Rs, 32, k0, 512, lane);
      short8 f3 = ldfrag(Rs, 48, k0, 512, lane);
      p0 = MFMA16(f3, f2, p0);      // (3,2)
      p1 = MFMA16(f3, f3, p1);      // (3,3)
    }
  }
  unsigned short* Pq = Pt + (size_t)(bh * NCH + c) * 4096;
  auto pwrite = [&](f32x4 pa, int tI, int tJ){
    int j  = tJ * 16 + (lane & 15);
    int i0 = tI * 16 + ((lane >> 4) << 2);
    #pragma unroll
    for (int r = 0; r < 4; ++r){
      int i = i0 + r;
      float v = (j < i) ? pa[r] * gpow[i] : 0.f;   // upper tiles -> pure zeros
      Pq[i * 64 + (j ^ ((i & 7) << 3))] = f2b(v);
    }
  };
  if      (w == 0){ pwrite(p0,0,0); pwrite(p1,1,0); pwrite(p2,1,1); pwrite(p0,0,1); }
  else if (w == 1){ pwrite(p0,2,0); pwrite(p1,2,1); pwrite(p2,2,2); pwrite(p0,0,2); }
  else if (w == 2){ pwrite(p0,3,0); pwrite(p1,3,1); pwrite(p0,0,3); pwrite(p1,1,2); }
  else            { pwrite(p0,3,2); pwrite(p1,3,3); pwrite(p0,1,3); pwrite(p1,2,3); }
}

// ---------------- Kernel 3: slim serial scan, 8 waves, 2 barriers/chunk ------------------
// w0-3: out (inter via gfrag from global QR + intra via ldfrag on global P~) + 2 state tiles.
// w4-7: 6 state tiles each (global u16 gather, round-8 proven). No Rs, no P~ compute.
__global__ __launch_bounds__(512, 1) void lattn_main(
    const unsigned short* __restrict__ QR,   // bf16 (BH,T,N) row-major
    const unsigned short* __restrict__ Pt,   // P~ swizzled images (BH,NCH,64x64)
    const float* __restrict__ V,
    const float* __restrict__ S_prev,
    const float* __restrict__ gammap,
    float* __restrict__ Out,
    float* __restrict__ Sfin)
{
  __shared__ __align__(16) unsigned short SbTs[16 * 512];  // bf16(S_start)^T [d][n]
  __shared__ __align__(16) unsigned short VTs[2][16 * 64]; // Vt^T [d][dt] dbuf
  __shared__ float gpow[65], gpinv[65];

  const int tid  = threadIdx.x;
  const int w    = tid >> 6;
  const int lane = tid & 63;
  const int bh   = blockIdx.x & 31;   // same bh -> same XCD
  const int dch  = blockIdx.x >> 5;
  const int d0   = dch * 16;
  const float g  = gammap[0];

  const unsigned short* QRbh = QR + (size_t)bh * Tn * Nn;
  const unsigned short* Ptbh = Pt + (size_t)bh * NCH * 4096;
  const float* Vbh = V + (size_t)bh * Tn * Dn;

  if (tid < 65){
    gpow[tid]  = powf(g,  (float)tid);
    gpinv[tid] = powf(g, -(float)tid);
  }

  // state tile split: w<4 own 2 tiles (base w*2), w>=4 own 6 tiles (base 8+(w-4)*6)
  const int snt = (w < 4) ? 2 : 6;
  const int sb  = (w < 4) ? w * 2 : 8 + (w - 4) * 6;
  f32x4 st[6];
  #pragma unroll
  for (int j = 0; j < 6; ++j) if (j < snt){
    int n = (sb + j) * 16 + (lane & 15);
    st[j] = *reinterpret_cast<const f32x4*>(
        S_prev + (size_t)bh * Nn * Dn + (size_t)n * Dn + d0 + ((lane >> 4) << 2));
  }
  __syncthreads();   // gpow ready
  const float g64 = gpow[64];

  // stage SbTs (S_start of chunk 0) + VT[0]
  #pragma unroll
  for (int j = 0; j < 6; ++j) if (j < snt){
    int n  = (sb + j) * 16 + (lane & 15);
    int dl = (lane >> 4) << 2;
    #pragma unroll
    for (int r = 0; r < 4; ++r){
      int d = dl + r;
      SbTs[d * 512 + (n ^ ((d & 7) << 3))] = f2b(st[j][r]);
    }
  }
  {
    int dtv = tid >> 3, dp = (tid & 7) << 1;
    const float* vp = Vbh + (size_t)dtv * Dn + d0 + dp;
    float sc = gpinv[dtv];
    VTs[0][ dp      * 64 + (dtv ^ (( dp      & 7) << 3))] = f2b(vp[0] * sc);
    VTs[0][(dp + 1) * 64 + (dtv ^ (((dp + 1) & 7) << 3))] = f2b(vp[1] * sc);
  }
  __syncthreads();

  for (int c = 0; c < NCH; ++c){
    const int t0 = c * CHn;
    const int vb = c & 1;
    const bool pf = (c + 1 < NCH);
    const unsigned short* Qc = QRbh + (size_t)t0 * Nn;   // L2/L3-hot

    float va0 = 0.f, va1 = 0.f;
    const int dtv_ = tid >> 3;
    if (pf){
      const float* vp = Vbh + (size_t)(t0 + CHn + dtv_) * Dn + d0 + ((tid & 7) << 1);
      va0 = vp[0]; va1 = vp[1];
    }

    // ================= Ph1 =================
    if (w < 4){
      // out i-tile w: inter = Sum_k SbT x R-frag (global), then gamma^i, then intra via P~
      f32x4 oacc = {0.f, 0.f, 0.f, 0.f};
      for (int kb = 0; kb < 16; ++kb){
        int k0 = kb * 32;
        short8 fs = ldfrag(SbTs, 0, k0, 512, lane);
        short8 fi = gfrag(Qc, w * 16, k0, lane);
        oacc = MFMA16(fs, fi, oacc);
      }
      float gi = gpow[w * 16 + (lane & 15)];
      #pragma unroll
      for (int r = 0; r < 4; ++r) oacc[r] *= gi;
      const unsigned short* Pq = Ptbh + (size_t)c * 4096;
      #pragma unroll
      for (int ks = 0; ks < 2; ++ks){
        short8 av = ldfrag(VTs[vb], 0, ks * 32, 64, lane);
        short8 bp = ldfrag(Pq, w * 16, ks * 32, 64, lane);
        oacc = MFMA16(av, bp, oacc);
      }
      int ti = t0 + w * 16 + (lane & 15);
      *reinterpret_cast<f32x4*>(
          Out + (size_t)bh * Tn * Dn + (size_t)ti * Dn + d0 + ((lane >> 4) << 2)) = oacc;
    }
    // state update (all waves; round-8 proven global u16 gather)
    #pragma unroll
    for (int ks = 0; ks < 2; ++ks){
      short8 av = ldfrag(VTs[vb], 0, ks * 32, 64, lane);
      #pragma unroll
      for (int j = 0; j < 6; ++j) if (j < snt){
        int n = (sb + j) * 16 + (lane & 15);
        const unsigned short* col = Qc + (size_t)(ks * 32 + ((lane >> 4) << 3)) * Nn + n;
        short8 bn;
        #pragma unroll
        for (int e = 0; e < 8; ++e) bn[e] = (short)col[(size_t)e * Nn];
        st[j] = MFMA16(av, bn, st[j]);
      }
    }
    #pragma unroll
    for (int j = 0; j < 6; ++j) if (j < snt)
      #pragma unroll
      for (int r = 0; r < 4; ++r) st[j][r] *= g64;
    __syncthreads();

    // ================= Ph2: SbT(c+1) + VT(c+1) =================
    #pragma unroll
    for (int j = 0; j < 6; ++j) if (j < snt){
      int n  = (sb + j) * 16 + (lane & 15);
      int dl = (lane >> 4) << 2;
      #pragma unroll
      for (int r = 0; r < 4; ++r){
        int d = dl + r;
        SbTs[d * 512 + (n ^ ((d & 7) << 3))] = f2b(st[j][r]);
      }
    }
    if (pf){
      int dp = (tid & 7) << 1;
      float sc = gpinv[dtv_];
      VTs[vb ^ 1][ dp      * 64 + (dtv_ ^ (( dp      & 7) << 3))] = f2b(va0 * sc);
      VTs[vb ^ 1][(dp + 1) * 64 + (dtv_ ^ (((dp + 1) & 7) << 3))] = f2b(va1 * sc);
    }
    __syncthreads();
  }

  // ---- epilogue: final state ----
  #pragma unroll
  for (int j = 0; j < 6; ++j) if (j < snt){
    int n = (sb + j) * 16 + (lane & 15);
    *reinterpret_cast<f32x4*>(
        Sfin + (size_t)bh * Nn * Dn + (size_t)n * Dn + d0 + ((lane >> 4) << 2)) = st[j];
  }
}

extern "C" void kernel_launch(void* const* d_in, const int* in_sizes, int n_in,
                              void* d_out, int out_size, void* d_ws, size_t ws_size,
                              hipStream_t stream){
  const float* Q      = (const float*)d_in[0];
  const float* V      = (const float*)d_in[1];
  const float* S_prev = (const float*)d_in[2];
  const float* freqs  = (const float*)d_in[3];
  const float* gamma  = (const float*)d_in[4];
  float* Out  = (float*)d_out;
  float* Sfin = Out + (size_t)BHn * Tn * Dn;
  unsigned short* QR = (unsigned short*)d_ws;                 // 64 MiB bf16
  unsigned short* Pt = QR + (size_t)BHn * Tn * Nn;            // +8 MiB P~ images

  rope_k<<<2048, 256, 0, stream>>>(Q, freqs, QR);
  pt_k<<<1024, 256, 0, stream>>>(QR, gamma, Pt);
  lattn_main<<<256, 512, 0, stream>>>(QR, Pt, V, S_prev, gamma, Out, Sfin);
}

// Round 12
// 219.598 us; speedup vs baseline: 1.0247x; 1.0247x over previous
//
#include <hip/hip_runtime.h>
#include <hip/hip_bf16.h>

typedef __attribute__((ext_vector_type(8))) short short8;
typedef __attribute__((ext_vector_type(4))) float f32x4;

#define MFMA16(a,b,c) __builtin_amdgcn_mfma_f32_16x16x32_bf16((a),(b),(c),0,0,0)

constexpr int BHn = 32;     // B*NH
constexpr int Tn  = 2048;
constexpr int Nn  = 512;
constexpr int Dn  = 128;
constexpr int CHn = 128;    // chunk length (halved serial-chain count vs 64)
constexpr int NCH = Tn / CHn;   // 16

static __device__ __forceinline__ unsigned short f2b(float x){
  __hip_bfloat16 h = __float2bfloat16(x);
  return *reinterpret_cast<unsigned short*>(&h);
}

// ---------------- Kernel 1: RoPE(Q) -> bf16 row-major QR ----------------
__global__ __launch_bounds__(256) void rope_k(const float* __restrict__ Q,
                                              const float* __restrict__ freqs,
                                              unsigned short* __restrict__ QR){
  int gid = blockIdx.x * 256 + threadIdx.x;
  int np  = gid & 255;
  int t   = gid >> 8;
  float tf = (float)t;
  float f1 = freqs[np], f2 = freqs[np + 256];
  float s1, c1, s2, c2;
  sincosf(tf * f1, &s1, &c1);
  sincosf(tf * f2, &s2, &c2);
  size_t off = (size_t)t * Nn + np;
  for (int bh = 0; bh < BHn; ++bh){
    size_t base = (size_t)bh * Tn * Nn + off;
    float q1 = Q[base], q2 = Q[base + 256];
    QR[base]       = f2b(q1 * c1 - q2 * s1);
    QR[base + 256] = f2b(q2 * c2 + q1 * s2);
  }
}

// ---------------- fragment loaders ----------------
// swizzled loader (LDS or global swizzled image): col ^= (row&7)<<3; swizzle stays
// within each 64-col band (XOR touches bits 3-5 only), so any ld multiple of 64 works.
__device__ __forceinline__ short8 ldfrag(const unsigned short* buf, int rowbase, int k0, int ld, int lane){
  int row = rowbase + (lane & 15);
  int col = (k0 + ((lane >> 4) << 3)) ^ ((row & 7) << 3);
  return *reinterpret_cast<const short8*>(buf + row * ld + col);
}
// global row-major frag: lane reads R[rowbase+(lane&15)][k0+(lane>>4)*8 ..+8]
__device__ __forceinline__ short8 gfrag(const unsigned short* Qc, int rowbase, int k0, int lane){
  return *reinterpret_cast<const short8*>(
      Qc + (size_t)(rowbase + (lane & 15)) * Nn + k0 + ((lane >> 4) << 3));
}
// staging writer: one even row-pair of R into swizzled Rs
__device__ __forceinline__ void stage_Rs(unsigned short* Rs, uint4 a, uint4 b, int dt, int n0){
  *reinterpret_cast<uint4*>(&Rs[ dt      * 512 + (n0 ^ (( dt      & 7) << 3))]) = a;
  *reinterpret_cast<uint4*>(&Rs[(dt + 1) * 512 + (n0 ^ (((dt + 1) & 7) << 3))]) = b;
}

// ---------------- Kernel 2 (parallel): diag 64-triangles of P~ -> [128][128] image -------
// grid 1024 = bh + 32*(c16) + 512*sub; block 256 (4 waves). Writes rows/cols [ro..ro+64)
// of image (bh,c16) with gamma power (i+ro). Upper tiles inside the band written as zeros.
__global__ __launch_bounds__(256) void pt_k(const unsigned short* __restrict__ QR,
                                            const float* __restrict__ gammap,
                                            unsigned short* __restrict__ Pt){
  __shared__ __align__(16) unsigned short Rs[64 * 512];
  __shared__ float gpow[129];
  const int tid = threadIdx.x, w = tid >> 6, lane = tid & 63;
  const int bh = blockIdx.x & 31, cc = (blockIdx.x >> 5) & 15, sub = blockIdx.x >> 9;
  const int ro = sub * 64;
  if (tid < 129) gpow[tid] = powf(gammap[0], (float)tid);
  const unsigned short* Qc = QR + (size_t)bh * Tn * Nn + (size_t)(cc * CHn + ro) * Nn;
  #pragma unroll
  for (int i = 0; i < 8; ++i){
    int p  = tid + i * 256;
    int dt = (p >> 6) << 1, n0 = (p & 63) << 3;
    const unsigned short* src = Qc + (size_t)dt * Nn + n0;
    uint4 a = *reinterpret_cast<const uint4*>(src);
    uint4 b = *reinterpret_cast<const uint4*>(src + Nn);
    stage_Rs(Rs, a, b, dt, n0);
  }
  __syncthreads();
  f32x4 p0 = {0.f,0.f,0.f,0.f}, p1 = p0, p2 = p0;
  for (int kb = 0; kb < 16; ++kb){
    int k0 = kb * 32;
    if (w == 0){
      short8 f0 = ldfrag(Rs,  0, k0, 512, lane);
      short8 f1 = ldfrag(Rs, 16, k0, 512, lane);
      p0 = MFMA16(f0, f0, p0);      // (0,0)
      p1 = MFMA16(f1, f0, p1);      // (1,0)
      p2 = MFMA16(f1, f1, p2);      // (1,1)
    } else if (w == 1){
      short8 f0 = ldfrag(Rs,  0, k0, 512, lane);
      short8 f1 = ldfrag(Rs, 16, k0, 512, lane);
      short8 f2 = ldfrag(Rs, 32, k0, 512, lane);
      p0 = MFMA16(f2, f0, p0);      // (2,0)
      p1 = MFMA16(f2, f1, p1);      // (2,1)
      p2 = MFMA16(f2, f2, p2);      // (2,2)
    } else if (w == 2){
      short8 f0 = ldfrag(Rs,  0, k0, 512, lane);
      short8 f1 = ldfrag(Rs, 16, k0, 512, lane);
      short8 f3 = ldfrag(Rs, 48, k0, 512, lane);
      p0 = MFMA16(f3, f0, p0);      // (3,0)
      p1 = MFMA16(f3, f1, p1);      // (3,1)
    } else {
      short8 f2 = ldfrag(Rs, 32, k0, 512, lane);
      short8 f3 = ldfrag(Rs, 48, k0, 512, lane);
      p0 = MFMA16(f3, f2, p0);      // (3,2)
      p1 = MFMA16(f3, f3, p1);      // (3,3)
    }
  }
  unsigned short* Pq = Pt + (size_t)(bh * NCH + cc) * (CHn * CHn);
  auto pwrite = [&](f32x4 pa, int tI, int tJ){
    int j  = tJ * 16 + (lane & 15);
    int i0 = tI * 16 + ((lane >> 4) << 2);
    #pragma unroll
    for (int r = 0; r < 4; ++r){
      int i = i0 + r;
      float v = (j < i) ? pa[r] * gpow[i + ro] : 0.f;
      Pq[(i + ro) * CHn + ro + (j ^ ((i & 7) << 3))] = f2b(v);   // (i+ro)&7 == i&7
    }
  };
  if      (w == 0){ pwrite(p0,0,0); pwrite(p1,1,0); pwrite(p2,1,1); pwrite(p0,0,1); }
  else if (w == 1){ pwrite(p0,2,0); pwrite(p1,2,1); pwrite(p2,2,2); pwrite(p0,0,2); }
  else if (w == 2){ pwrite(p0,3,0); pwrite(p1,3,1); pwrite(p0,0,3); pwrite(p1,1,2); }
  else            { pwrite(p0,3,2); pwrite(p1,3,3); pwrite(p0,1,3); pwrite(p1,2,3); }
}

// ---------------- Kernel 3 (parallel): off-diag 64x64 block of P~ ------------------------
// grid 512 = bh + 32*c16; rows 64..127 x cols 0..63 of the image: full matmul via gfrag.
__global__ __launch_bounds__(256) void po_k(const unsigned short* __restrict__ QR,
                                            const float* __restrict__ gammap,
                                            unsigned short* __restrict__ Pt){
  __shared__ float gpow[129];
  const int tid = threadIdx.x, w = tid >> 6, lane = tid & 63;
  const int bh = blockIdx.x & 31, cc = blockIdx.x >> 5;
  if (tid < 129) gpow[tid] = powf(gammap[0], (float)tid);
  __syncthreads();
  const unsigned short* QB = QR + (size_t)bh * Tn * Nn + (size_t)(cc * CHn) * Nn; // rows j
  const unsigned short* QA = QB + (size_t)64 * Nn;                                 // rows 64+i
  f32x4 acc[4] = {{0.f,0.f,0.f,0.f},{0.f,0.f,0.f,0.f},{0.f,0.f,0.f,0.f},{0.f,0.f,0.f,0.f}};
  for (int kb = 0; kb < 16; ++kb){
    int k0 = kb * 32;
    short8 fa = gfrag(QA, w * 16, k0, lane);
    #pragma unroll
    for (int t = 0; t < 4; ++t){
      short8 fb = gfrag(QB, t * 16, k0, lane);
      acc[t] = MFMA16(fa, fb, acc[t]);   // C row = 64+i (A), col = j (B)
    }
  }
  unsigned short* Pq = Pt + (size_t)(bh * NCH + cc) * (CHn * CHn);
  #pragma unroll
  for (int t = 0; t < 4; ++t){
    int j  = t * 16 + (lane & 15);
    int i0 = w * 16 + ((lane >> 4) << 2);
    #pragma unroll
    for (int r = 0; r < 4; ++r){
      int i = i0 + r;
      float v = acc[t][r] * gpow[64 + i];
      Pq[(64 + i) * CHn + (j ^ ((i & 7) << 3))] = f2b(v);   // (64+i)&7 == i&7
    }
  }
}

// ---------------- Kernel 4: slim serial scan, CH=128, 8 waves, 2 barriers/chunk ----------
// w0-3: TWO out i-tile chains (w, w+4) + 2 state tiles. w4-7: 6 state tiles each.
__global__ __launch_bounds__(512, 1) void lattn_main(
    const unsigned short* __restrict__ QR,   // bf16 (BH,T,N) row-major
    const unsigned short* __restrict__ Pt,   // P~ swizzled images (BH,NCH,128x128)
    const float* __restrict__ V,
    const float* __restrict__ S_prev,
    const float* __restrict__ gammap,
    float* __restrict__ Out,
    float* __restrict__ Sfin)
{
  __shared__ __align__(16) unsigned short SbTs[16 * 512];   // bf16(S_start)^T [d][n]
  __shared__ __align__(16) unsigned short VTs[2][16 * 128]; // Vt^T [d][dt] dbuf, dt 0..127
  __shared__ float gpow[129], gpinv[129];

  const int tid  = threadIdx.x;
  const int w    = tid >> 6;
  const int lane = tid & 63;
  const int bh   = blockIdx.x & 31;   // same bh -> same XCD
  const int dch  = blockIdx.x >> 5;
  const int d0   = dch * 16;
  const float g  = gammap[0];

  const unsigned short* QRbh = QR + (size_t)bh * Tn * Nn;
  const unsigned short* Ptbh = Pt + (size_t)bh * NCH * (CHn * CHn);
  const float* Vbh = V + (size_t)bh * Tn * Dn;

  if (tid < 129){
    gpow[tid]  = powf(g,  (float)tid);
    gpinv[tid] = powf(g, -(float)tid);
  }

  // state tile split: w<4 own 2 tiles (base w*2), w>=4 own 6 tiles (base 8+(w-4)*6)
  const int snt = (w < 4) ? 2 : 6;
  const int sb  = (w < 4) ? w * 2 : 8 + (w - 4) * 6;
  f32x4 st[6];
  #pragma unroll
  for (int j = 0; j < 6; ++j) if (j < snt){
    int n = (sb + j) * 16 + (lane & 15);
    st[j] = *reinterpret_cast<const f32x4*>(
        S_prev + (size_t)bh * Nn * Dn + (size_t)n * Dn + d0 + ((lane >> 4) << 2));
  }
  __syncthreads();   // gpow ready
  const float g128 = gpow[128];

  // stage SbTs (S_start of chunk 0) + VT[0]
  #pragma unroll
  for (int j = 0; j < 6; ++j) if (j < snt){
    int n  = (sb + j) * 16 + (lane & 15);
    int dl = (lane >> 4) << 2;
    #pragma unroll
    for (int r = 0; r < 4; ++r){
      int d = dl + r;
      SbTs[d * 512 + (n ^ ((d & 7) << 3))] = f2b(st[j][r]);
    }
  }
  {
    int dtv = tid >> 2, dp0 = (tid & 3) << 2;   // 128 dt x 4 d per thread
    f32x4 v4 = *reinterpret_cast<const f32x4*>(Vbh + (size_t)dtv * Dn + d0 + dp0);
    float sc = gpinv[dtv];
    #pragma unroll
    for (int r = 0; r < 4; ++r){
      int d = dp0 + r;
      VTs[0][d * 128 + (dtv ^ ((d & 7) << 3))] = f2b(v4[r] * sc);
    }
  }
  __syncthreads();

  for (int c = 0; c < NCH; ++c){
    const int t0 = c * CHn;
    const int vb = c & 1;
    const bool pf = (c + 1 < NCH);
    const unsigned short* Qc = QRbh + (size_t)t0 * Nn;   // L2-hot

    // V prefetch for chunk c+1
    f32x4 va4 = {0.f, 0.f, 0.f, 0.f};
    const int dtv_ = tid >> 2, dp0_ = (tid & 3) << 2;
    if (pf)
      va4 = *reinterpret_cast<const f32x4*>(Vbh + (size_t)(t0 + CHn + dtv_) * Dn + d0 + dp0_);

    // ================= Ph1 =================
    if (w < 4){
      // two independent out chains: i-tiles it0 = w (rows < 64), it1 = w+4 (rows >= 64)
      const int it0 = w, it1 = w + 4;
      f32x4 o0 = {0.f,0.f,0.f,0.f}, o1 = o0;
      for (int kb = 0; kb < 16; ++kb){
        int k0 = kb * 32;
        short8 fs = ldfrag(SbTs, 0, k0, 512, lane);
        short8 fa = gfrag(Qc, it0 * 16, k0, lane);
        short8 fb = gfrag(Qc, it1 * 16, k0, lane);
        o0 = MFMA16(fs, fa, o0);
        o1 = MFMA16(fs, fb, o1);
      }
      float g0 = gpow[it0 * 16 + (lane & 15)];
      float g1 = gpow[it1 * 16 + (lane & 15)];
      #pragma unroll
      for (int r = 0; r < 4; ++r){ o0[r] *= g0; o1[r] *= g1; }
      // intra via global P~ image: it0 needs ks 0..1, it1 needs ks 0..3
      const unsigned short* Pq = Ptbh + (size_t)c * (CHn * CHn);
      #pragma unroll
      for (int ks = 0; ks < 4; ++ks){
        short8 av = ldfrag(VTs[vb], 0, ks * 32, 128, lane);
        if (ks < 2){
          short8 b0 = ldfrag(Pq, it0 * 16, ks * 32, CHn, lane);
          o0 = MFMA16(av, b0, o0);
        }
        short8 b1 = ldfrag(Pq, it1 * 16, ks * 32, CHn, lane);
        o1 = MFMA16(av, b1, o1);
      }
      int ti0 = t0 + it0 * 16 + (lane & 15);
      int ti1 = t0 + it1 * 16 + (lane & 15);
      *reinterpret_cast<f32x4*>(
          Out + (size_t)bh * Tn * Dn + (size_t)ti0 * Dn + d0 + ((lane >> 4) << 2)) = o0;
      *reinterpret_cast<f32x4*>(
          Out + (size_t)bh * Tn * Dn + (size_t)ti1 * Dn + d0 + ((lane >> 4) << 2)) = o1;
    }
    // state update (all waves; global u16 gather), ks 0..3 over dt 0..127
    #pragma unroll
    for (int ks = 0; ks < 4; ++ks){
      short8 av = ldfrag(VTs[vb], 0, ks * 32, 128, lane);
      #pragma unroll
      for (int j = 0; j < 6; ++j) if (j < snt){
        int n = (sb + j) * 16 + (lane & 15);
        const unsigned short* col = Qc + (size_t)(ks * 32 + ((lane >> 4) << 3)) * Nn + n;
        short8 bn;
        #pragma unroll
        for (int e = 0; e < 8; ++e) bn[e] = (short)col[(size_t)e * Nn];
        st[j] = MFMA16(av, bn, st[j]);
      }
    }
    #pragma unroll
    for (int j = 0; j < 6; ++j) if (j < snt)
      #pragma unroll
      for (int r = 0; r < 4; ++r) st[j][r] *= g128;
    __syncthreads();

    // ================= Ph2: SbT(c+1) + VT(c+1) =================
    #pragma unroll
    for (int j = 0; j < 6; ++j) if (j < snt){
      int n  = (sb + j) * 16 + (lane & 15);
      int dl = (lane >> 4) << 2;
      #pragma unroll
      for (int r = 0; r < 4; ++r){
        int d = dl + r;
        SbTs[d * 512 + (n ^ ((d & 7) << 3))] = f2b(st[j][r]);
      }
    }
    if (pf){
      float sc = gpinv[dtv_];
      #pragma unroll
      for (int r = 0; r < 4; ++r){
        int d = dp0_ + r;
        VTs[vb ^ 1][d * 128 + (dtv_ ^ ((d & 7) << 3))] = f2b(va4[r] * sc);
      }
    }
    __syncthreads();
  }

  // ---- epilogue: final state ----
  #pragma unroll
  for (int j = 0; j < 6; ++j) if (j < snt){
    int n = (sb + j) * 16 + (lane & 15);
    *reinterpret_cast<f32x4*>(
        Sfin + (size_t)bh * Nn * Dn + (size_t)n * Dn + d0 + ((lane >> 4) << 2)) = st[j];
  }
}

extern "C" void kernel_launch(void* const* d_in, const int* in_sizes, int n_in,
                              void* d_out, int out_size, void* d_ws, size_t ws_size,
                              hipStream_t stream){
  const float* Q      = (const float*)d_in[0];
  const float* V      = (const float*)d_in[1];
  const float* S_prev = (const float*)d_in[2];
  const float* freqs  = (const float*)d_in[3];
  const float* gamma  = (const float*)d_in[4];
  float* Out  = (float*)d_out;
  float* Sfin = Out + (size_t)BHn * Tn * Dn;
  unsigned short* QR = (unsigned short*)d_ws;                 // 64 MiB bf16
  unsigned short* Pt = QR + (size_t)BHn * Tn * Nn;            // +16 MiB P~ images

  rope_k<<<2048, 256, 0, stream>>>(Q, freqs, QR);
  pt_k<<<1024, 256, 0, stream>>>(QR, gamma, Pt);
  po_k<<<512, 256, 0, stream>>>(QR, gamma, Pt);
  lattn_main<<<256, 512, 0, stream>>>(QR, Pt, V, S_prev, gamma, Out, Sfin);
}